// Round 1
// baseline (378.106 us; speedup 1.0000x reference)
//
#include <hip/hip_runtime.h>
#include <math.h>

// Problem constants (B,S,H,D,P fixed by the reference).
#define B_ 16
#define S_ 512
#define H_ 12
#define D_ 768
#define P_ 256
#define K_ 51
#define CH_ 16            // s-rows per k2 chunk
#define NCHUNK_ (S_/CH_)  // 32

// Monotonic float->uint key: larger float <=> larger unsigned.
__device__ __forceinline__ unsigned okey(float f) {
  unsigned u = __float_as_uint(f);
  return (u & 0x80000000u) ? ~u : (u | 0x80000000u);
}

// k1: one WAVE per (b,t) attention row. Head-average (coalesced float4
// streaming), exact top-K select via wave-uniform MSB-first bit bisection on
// ballots (no LDS, no atomics, no waitcnt drains). Emits per-row selection
// bitmask (8x u64, column-interleaved: bit(lane) of word i covers column
// 4*lane+i for i<4, 256+4*lane+(i-4) for i>=4) plus invcnt.
__global__ __launch_bounds__(256) void k1_topk_mask(
    const float* __restrict__ attn, unsigned long long* __restrict__ maskbuf,
    float* __restrict__ invbuf) {
  const int tid = threadIdx.x;
  const int wv = tid >> 6;
  const int lane = tid & 63;
  const int bt = blockIdx.x * 4 + wv;
  const int b = bt >> 9;            // S_ == 512
  const int t = bt & (S_ - 1);

  // --- head-average: lane owns columns {4*lane+i, 256+4*lane+i} ---
  const float* base = attn + (((size_t)b * H_) * S_ + t) * S_;
  float a[8] = {0.f, 0.f, 0.f, 0.f, 0.f, 0.f, 0.f, 0.f};
  #pragma unroll
  for (int h = 0; h < H_; ++h) {
    const float* r = base + (size_t)h * (S_ * S_);
    const float4 u = *(const float4*)(r + 4 * lane);
    const float4 v = *(const float4*)(r + 256 + 4 * lane);
    a[0] += u.x; a[1] += u.y; a[2] += u.z; a[3] += u.w;
    a[4] += v.x; a[5] += v.y; a[6] += v.z; a[7] += v.w;
  }
  unsigned k[8];
  #pragma unroll
  for (int i = 0; i < 8; ++i) {
    a[i] *= (1.0f / (float)H_);
    k[i] = okey(a[i]);
  }

  // --- row-wide positive count via ballots (wave-uniform result) ---
  int p = 0;
  #pragma unroll
  for (int i = 0; i < 8; ++i) p += __popcll(__ballot(a[i] > 0.f));

  bool sel[8];
  float invcnt;
  if (p >= 1 && p < K_) {
    // kept set == all positive entries (all inside the top-K)
    #pragma unroll
    for (int i = 0; i < 8; ++i) sel[i] = (a[i] > 0.f);
    invcnt = 1.0f / (float)p;
  } else {
    // Exact top-K via bitwise radix bisection. Invariant: keys whose bits
    // above the current position exceed `prefix` are already kept; `rem` of
    // the keys matching `prefix` remain to be chosen.
    unsigned prefix = 0;
    int rem = K_;
    bool done = false;
    unsigned dmask = 0, thr = 0;
    for (int bpos = 31; bpos >= 0; --bpos) {
      const unsigned bit = 1u << bpos;
      const unsigned mb = ~(bit - 1u);       // bits bpos..31
      const unsigned cand = prefix | bit;
      int cnt = 0;
      #pragma unroll
      for (int i = 0; i < 8; ++i)
        cnt += __popcll(__ballot((k[i] & mb) == cand));
      if (cnt == rem) { done = true; dmask = mb; thr = cand; break; }
      if (cnt > rem) prefix = cand;
      else rem -= cnt;
    }
    if (done) {
      #pragma unroll
      for (int i = 0; i < 8; ++i) sel[i] = (k[i] & dmask) >= thr;
    } else {
      // Full-key ties at prefix: keep all k > T plus `rem` lowest-index ties
      // (column order: first half before second half, then 4*lane+i order).
      const unsigned T = prefix;
      unsigned long long mm[8];
      #pragma unroll
      for (int i = 0; i < 8; ++i) mm[i] = __ballot(k[i] == T);
      const unsigned long long lt = ((unsigned long long)1 << lane) - 1ull;
      int fh = 0;
      #pragma unroll
      for (int i = 0; i < 4; ++i) fh += __popcll(mm[i]);
      #pragma unroll
      for (int i = 0; i < 8; ++i) {
        sel[i] = (k[i] > T);
        if (k[i] == T) {
          int r = 0;
          if (i < 4) {
            #pragma unroll
            for (int i2 = 0; i2 < 4; ++i2) r += __popcll(mm[i2] & lt);
            for (int i2 = 0; i2 < i; ++i2) r += (int)((mm[i2] >> lane) & 1ull);
          } else {
            r = fh;
            #pragma unroll
            for (int i2 = 4; i2 < 8; ++i2) r += __popcll(mm[i2] & lt);
            for (int i2 = 4; i2 < i; ++i2) r += (int)((mm[i2] >> lane) & 1ull);
          }
          if (r < rem) sel[i] = true;
        }
      }
    }
    invcnt = 1.0f / (float)K_;
  }

  // --- emit selection bitmask + invcnt (plain stores, no atomics) ---
  unsigned long long m[8];
  #pragma unroll
  for (int i = 0; i < 8; ++i) m[i] = __ballot(sel[i]);
  if (lane == 0) {
    ulonglong2* mp = (ulonglong2*)(maskbuf + (size_t)bt * 8);
    mp[0] = ulonglong2{m[0], m[1]};
    mp[1] = ulonglong2{m[2], m[3]};
    mp[2] = ulonglong2{m[4], m[5]};
    mp[3] = ulonglong2{m[6], m[7]};
    invbuf[bt] = invcnt;
  }
}

// k1b: column-sum of the selection bit-matrix with per-row weights:
// w[b,s] = sum_t bit(t,s) * inv[t]; coef[b,s] = (eta + (1-eta)*w)/S.
// grid (2, B): each block stages all 512 rows' masks (32 KB) + inv (2 KB) in
// LDS; thread owns one s column. LDS reads are 16-lane broadcasts (conflict
// free); replaces ~417K contended global atomics with a deterministic sum.
__global__ __launch_bounds__(256) void k1b_colsum(
    const unsigned long long* __restrict__ maskbuf,
    const float* __restrict__ invbuf, const float* __restrict__ node_eta,
    float* __restrict__ coef) {
  const int half = blockIdx.x;  // 0..1 -> s in [256*half, 256*half+256)
  const int b = blockIdx.y;
  const int tid = threadIdx.x;
  __shared__ unsigned long long ms[S_][8];  // 32 KB
  __shared__ float inv[S_];                 // 2 KB

  const ulonglong2* mrow2 = (const ulonglong2*)(maskbuf + (size_t)b * S_ * 8);
  ulonglong2* lds2 = (ulonglong2*)&ms[0][0];
  #pragma unroll
  for (int j = 0; j < 8; ++j) lds2[tid + 256 * j] = mrow2[tid + 256 * j];
  inv[tid] = invbuf[b * S_ + tid];
  inv[tid + 256] = invbuf[b * S_ + tid + 256];
  __syncthreads();

  const int s = half * 256 + tid;
  const int wi = (s < 256) ? (s & 3) : 4 + (s & 3);
  const unsigned long long bitm = 1ull << ((s & 255) >> 2);
  float w = 0.f;
  #pragma unroll 8
  for (int tt = 0; tt < S_; ++tt)
    if (ms[tt][wi] & bitm) w += inv[tt];

  const float eta = node_eta[0];
  coef[b * S_ + s] = (eta + (1.0f - eta) * w) * (1.0f / (float)S_);
}

// x[b,d] = sum_s coef[b,s] * hidden[b,s,d]
__global__ __launch_bounds__(192) void k2_weighted_sum(
    const float* __restrict__ hidden, const float* __restrict__ coef,
    float* __restrict__ x) {
  const int chunk = blockIdx.x;
  const int b = blockIdx.y;
  const int tid = threadIdx.x;  // 0..191 -> d = 4*tid .. 4*tid+3 (D_ = 768)
  __shared__ float cs[CH_];
  if (tid < CH_) cs[tid] = coef[b * S_ + chunk * CH_ + tid];
  __syncthreads();
  const float* hb = hidden + ((size_t)b * S_ + (size_t)chunk * CH_) * D_ + 4 * tid;
  float4 acc = make_float4(0.f, 0.f, 0.f, 0.f);
  #pragma unroll
  for (int s = 0; s < CH_; ++s) {
    const float4 v = *(const float4*)(hb + (size_t)s * D_);
    const float c = cs[s];
    acc.x += c * v.x; acc.y += c * v.y; acc.z += c * v.z; acc.w += c * v.w;
  }
  float* xp = x + b * D_ + 4 * tid;
  atomicAdd(xp + 0, acc.x);
  atomicAdd(xp + 1, acc.y);
  atomicAdd(xp + 2, acc.z);
  atomicAdd(xp + 3, acc.w);
}

// k3a: t[b,p] = tanh(x[b,:]@W_node[:,p] + b_node[p]) for a 32-col slice.
// grid (8, B), block 256 = 16 float2-cols x 16 d-groups of 48.
__global__ __launch_bounds__(256) void k3a_tanh_matvec(
    const float* __restrict__ x, const float* __restrict__ W_node,
    const float* __restrict__ b_node, float* __restrict__ tbuf) {
  const int j = blockIdx.x;   // 32-column slice
  const int b = blockIdx.y;
  const int tid = threadIdx.x;
  const int pp = tid & 15;    // float2 column pair
  const int g = tid >> 4;     // d-group
  __shared__ float xs[D_];
  __shared__ float part[16][32];
  for (int d = tid; d < D_; d += 256) xs[d] = x[b * D_ + d];
  __syncthreads();
  const float* Wp = W_node + 32 * j + 2 * pp;
  float2 acc = make_float2(0.f, 0.f);
  const int d0 = 48 * g;
  #pragma unroll 8
  for (int dd = 0; dd < 48; ++dd) {
    const int d = d0 + dd;
    const float2 wv = *(const float2*)(Wp + (size_t)d * P_);
    const float xv = xs[d];
    acc.x += xv * wv.x; acc.y += xv * wv.y;
  }
  *(float2*)&part[g][2 * pp] = acc;
  __syncthreads();
  if (tid < 32) {
    float s = 0.f;
    #pragma unroll
    for (int gg = 0; gg < 16; ++gg) s += part[gg][tid];
    const int pcol = 32 * j + tid;
    tbuf[b * P_ + pcol] = tanhf(s + b_node[pcol]);
  }
}

// k3bc: o[b,p] = t[b,:]@W_fc[:,p] + b_fc[p], then LayerNorm over P.
// One block per b; thread owns column p; W_fc read column-major coalesced
// (L2-resident, 256 KB).
__global__ __launch_bounds__(256) void k3bc_fc_ln(
    const float* __restrict__ tbuf, const float* __restrict__ W_fc,
    const float* __restrict__ b_fc, const float* __restrict__ gamma,
    const float* __restrict__ beta, float* __restrict__ out) {
  const int b = blockIdx.x;
  const int tid = threadIdx.x;
  __shared__ float ts[P_];
  __shared__ float red[4];
  ts[tid] = tbuf[b * P_ + tid];
  __syncthreads();
  float acc = 0.f;
  #pragma unroll 8
  for (int q = 0; q < P_; ++q) acc += ts[q] * W_fc[(size_t)q * P_ + tid];
  const float o = acc + b_fc[tid];

  float s = o;
  #pragma unroll
  for (int off = 32; off > 0; off >>= 1) s += __shfl_down(s, off, 64);
  const int wave = tid >> 6, lane = tid & 63;
  if (lane == 0) red[wave] = s;
  __syncthreads();
  const float mu = (red[0] + red[1] + red[2] + red[3]) * (1.0f / (float)P_);
  __syncthreads();
  const float dv = o - mu;
  float s2 = dv * dv;
  #pragma unroll
  for (int off = 32; off > 0; off >>= 1) s2 += __shfl_down(s2, off, 64);
  if (lane == 0) red[wave] = s2;
  __syncthreads();
  const float var = (red[0] + red[1] + red[2] + red[3]) * (1.0f / (float)P_);
  const float inv = 1.0f / sqrtf(var + 1e-5f);
  out[b * P_ + tid] = dv * inv * gamma[tid] + beta[tid];
}

extern "C" void kernel_launch(void* const* d_in, const int* in_sizes, int n_in,
                              void* d_out, int out_size, void* d_ws, size_t ws_size,
                              hipStream_t stream) {
  (void)in_sizes; (void)n_in; (void)out_size; (void)ws_size;
  const float* hidden   = (const float*)d_in[0];  // [B,S,D]
  const float* attn     = (const float*)d_in[1];  // [B,H,S,S]
  /* d_in[2] = length (== S, unused) */
  const float* W_node   = (const float*)d_in[3];  // [D,P]
  const float* b_node   = (const float*)d_in[4];  // [P]
  const float* node_eta = (const float*)d_in[5];  // [1]
  const float* W_fc     = (const float*)d_in[6];  // [P,P]
  const float* b_fc     = (const float*)d_in[7];  // [P]
  const float* gamma    = (const float*)d_in[8];  // [P]
  const float* beta     = (const float*)d_in[9];  // [P]
  float* out = (float*)d_out;                     // [B,P] fp32

  // Workspace layout (16B-aligned pieces, ~640 KB total):
  unsigned long long* maskbuf = (unsigned long long*)d_ws;   // B*S*8 u64 (512 KB)
  float* invbuf = (float*)(maskbuf + (size_t)B_ * S_ * 8);   // B*S (32 KB)
  float* coef   = invbuf + B_ * S_;                          // B*S (32 KB)
  float* x      = coef + B_ * S_;                            // B*D (48 KB)
  float* tbuf   = x + B_ * D_;                               // B*P (16 KB)

  hipMemsetAsync(x, 0, (size_t)(B_ * D_) * sizeof(float), stream);

  k1_topk_mask<<<(B_ * S_) / 4, 256, 0, stream>>>(attn, maskbuf, invbuf);
  k1b_colsum<<<dim3(2, B_), 256, 0, stream>>>(maskbuf, invbuf, node_eta, coef);
  k2_weighted_sum<<<dim3(NCHUNK_, B_), 192, 0, stream>>>(hidden, coef, x);
  k3a_tanh_matvec<<<dim3(8, B_), 256, 0, stream>>>(x, W_node, b_node, tbuf);
  k3bc_fc_ln<<<B_, 256, 0, stream>>>(tbuf, W_fc, b_fc, gamma, beta, out);
}